// Round 2
// baseline (303.833 us; speedup 1.0000x reference)
//
#include <hip/hip_runtime.h>

typedef __attribute__((ext_vector_type(8))) short s16x8;
typedef __attribute__((ext_vector_type(4))) float f32x4;

#define CCH 128

__device__ __forceinline__ ushort f2bf(float f) {
  uint u = __float_as_uint(f);
  u += 0x7fffu + ((u >> 16) & 1u);
  return (ushort)(u >> 16);
}

// swizzled index into a [row][128] bf16 LDS tile
__device__ __forceinline__ int swz(int row, int col) {
  return (row << 7) | (col ^ ((row & 7) << 3));
}

__global__ __launch_bounds__(256) void prep_w2(const float* __restrict__ w2,
                                               ushort* __restrict__ w2b) {
  int i = blockIdx.x * 256 + threadIdx.x;  // 16 blocks, 4 elems each
  float4 a = ((const float4*)w2)[i];
  ushort4 o;
  o.x = f2bf(a.x); o.y = f2bf(a.y); o.z = f2bf(a.z); o.w = f2bf(a.w);
  ((ushort4*)w2b)[i] = o;
}

// 1024 blocks: block i covers one (b,ch) channel image (65536 floats)
__global__ __launch_bounds__(256) void stats_partial(const float* __restrict__ x,
                                                     float* __restrict__ partials) {
  const float4* xp = (const float4*)(x + ((size_t)blockIdx.x << 16));
  const int tid = threadIdx.x;
  float s1 = 0.f, s2 = 0.f;
#pragma unroll 8
  for (int i = 0; i < 64; ++i) {
    float4 v = xp[i * 256 + tid];
    s1 += v.x + v.y + v.z + v.w;
    s2 += v.x * v.x + v.y * v.y + v.z * v.z + v.w * v.w;
  }
#pragma unroll
  for (int off = 32; off > 0; off >>= 1) {
    s1 += __shfl_down(s1, off);
    s2 += __shfl_down(s2, off);
  }
  __shared__ float r1[4], r2[4];
  const int wv = tid >> 6;
  if ((tid & 63) == 0) { r1[wv] = s1; r2[wv] = s2; }
  __syncthreads();
  if (tid == 0) {
    partials[blockIdx.x * 2]     = r1[0] + r1[1] + r1[2] + r1[3];
    partials[blockIdx.x * 2 + 1] = r2[0] + r2[1] + r2[2] + r2[3];
  }
}

// 64 threads: one per (b,g). scale/shift per (b,c).
__global__ void stats_finalize(const float* __restrict__ partials,
                               const float* __restrict__ gn_w,
                               const float* __restrict__ gn_b,
                               float* __restrict__ scale, float* __restrict__ shift) {
  const int t = threadIdx.x;
  float s1 = 0.f, s2 = 0.f;
#pragma unroll
  for (int i = 0; i < 16; ++i) {
    s1 += partials[(t * 16 + i) * 2];
    s2 += partials[(t * 16 + i) * 2 + 1];
  }
  const float invN = 1.0f / 1048576.0f;
  const float mean = s1 * invN;
  const float var = s2 * invN - mean * mean;
  const float rstd = rsqrtf(var + 1e-5f);
  const int b = t >> 3, g = t & 7;
  for (int i = 0; i < 16; ++i) {
    const int c = g * 16 + i;
    const float sc = rstd * gn_w[c];
    scale[b * CCH + c] = sc;
    shift[b * CCH + c] = gn_b[c] - mean * sc;
  }
}

// Fold GN into GEMM1: W1'[b][o][c] = w1[o][c]*scale[b][c] (bf16),
// c1[b][o] = sum_c w1[o][c]*shift[b][c] + b1[o]. 1024 blocks x 128 thr.
__global__ __launch_bounds__(128) void fold_w1(const float* __restrict__ w1,
                                               const float* __restrict__ b1,
                                               const float* __restrict__ scale,
                                               const float* __restrict__ shift,
                                               ushort* __restrict__ W1b,
                                               float* __restrict__ c1) {
  const int b = blockIdx.x >> 7, o = blockIdx.x & 127, c = threadIdx.x;
  const float wv = w1[o * CCH + c];
  W1b[(b << 14) + o * CCH + c] = f2bf(wv * scale[b * CCH + c]);
  float s = wv * shift[b * CCH + c];
#pragma unroll
  for (int off = 32; off > 0; off >>= 1) s += __shfl_down(s, off);
  __shared__ float tmp[2];
  if ((threadIdx.x & 63) == 0) tmp[threadIdx.x >> 6] = s;
  __syncthreads();
  if (threadIdx.x == 0) c1[(b << 7) + o] = tmp[0] + tmp[1] + b1[o];
}

// 16384 one-wave blocks (8 batches x 2048 tiles of 32 pixels). No barriers:
// every wave is an independent pipeline -> no device-wide phase locking.
__global__ __launch_bounds__(64, 3) void wave_fused(
    const float* __restrict__ x, const ushort* __restrict__ W1b,
    const ushort* __restrict__ w2b, const float* __restrict__ c1,
    const float* __restrict__ b2, float* __restrict__ out) {
  __shared__ __align__(16) ushort sB[32 * CCH];  // 8 KiB
  const int lane = threadIdx.x;
  const int b = blockIdx.x >> 11;
  const int p0 = (blockIdx.x & 2047) << 5;
  const int fl = lane & 15, fh = lane >> 4;

  // ---- stage: raw x -> bf16 LDS [pixel 32][chan 128], swizzled ----
  {
    const int p = lane & 31;
    const int ch0 = (lane >> 5) << 6;  // 0 or 64
    const float* xb = x + (((size_t)b * CCH) << 16) + p0 + p;
#pragma unroll
    for (int i = 0; i < 16; ++i) {
      const int c = ch0 + i * 4;
      const float v0 = xb[(size_t)(c + 0) << 16];
      const float v1 = xb[(size_t)(c + 1) << 16];
      const float v2 = xb[(size_t)(c + 2) << 16];
      const float v3 = xb[(size_t)(c + 3) << 16];
      ushort4 pk;
      pk.x = f2bf(v0); pk.y = f2bf(v1); pk.z = f2bf(v2); pk.w = f2bf(v3);
      *(ushort4*)&sB[swz(p, c)] = pk;
    }
  }

  // ---- GEMM1: H = W1' . x + c1, relu ----
  f32x4 acc[8][2];
#pragma unroll
  for (int to = 0; to < 8; ++to)
#pragma unroll
    for (int tp = 0; tp < 2; ++tp) acc[to][tp] = (f32x4){0.f, 0.f, 0.f, 0.f};

  const ushort* w1p = W1b + ((size_t)b << 14);
#pragma unroll
  for (int k0 = 0; k0 < 4; ++k0) {
    const int kb = k0 * 32 + fh * 8;
    const s16x8 bt0 = *(const s16x8*)&sB[swz(fl, kb)];
    const s16x8 bt1 = *(const s16x8*)&sB[swz(16 + fl, kb)];
#pragma unroll
    for (int to = 0; to < 8; ++to) {
      const s16x8 a = *(const s16x8*)(w1p + (to * 16 + fl) * CCH + kb);
      acc[to][0] = __builtin_amdgcn_mfma_f32_16x16x32_bf16(a, bt0, acc[to][0], 0, 0, 0);
      acc[to][1] = __builtin_amdgcn_mfma_f32_16x16x32_bf16(a, bt1, acc[to][1], 0, 0, 0);
    }
  }

  // ---- writeback H (bias incl. b1) + relu -> sB (program-order safe, 1 wave) ----
  const float* c1b = c1 + (b << 7);
#pragma unroll
  for (int to = 0; to < 8; ++to) {
    const int ob = to * 16 + fh * 4;
    const float4 cc = *(const float4*)(c1b + ob);
#pragma unroll
    for (int tp = 0; tp < 2; ++tp) {
      ushort4 pk;
      pk.x = f2bf(fmaxf(acc[to][tp][0] + cc.x, 0.f));
      pk.y = f2bf(fmaxf(acc[to][tp][1] + cc.y, 0.f));
      pk.z = f2bf(fmaxf(acc[to][tp][2] + cc.z, 0.f));
      pk.w = f2bf(fmaxf(acc[to][tp][3] + cc.w, 0.f));
      *(ushort4*)&sB[swz(tp * 16 + fl, ob)] = pk;
    }
  }

  // ---- GEMM2: ffn = w2 . H ----
  f32x4 acc2[8][2];
#pragma unroll
  for (int to = 0; to < 8; ++to)
#pragma unroll
    for (int tp = 0; tp < 2; ++tp) acc2[to][tp] = (f32x4){0.f, 0.f, 0.f, 0.f};

#pragma unroll
  for (int k0 = 0; k0 < 4; ++k0) {
    const int kb = k0 * 32 + fh * 8;
    const s16x8 bt0 = *(const s16x8*)&sB[swz(fl, kb)];
    const s16x8 bt1 = *(const s16x8*)&sB[swz(16 + fl, kb)];
#pragma unroll
    for (int to = 0; to < 8; ++to) {
      const s16x8 a = *(const s16x8*)(w2b + (to * 16 + fl) * CCH + kb);
      acc2[to][0] = __builtin_amdgcn_mfma_f32_16x16x32_bf16(a, bt0, acc2[to][0], 0, 0, 0);
      acc2[to][1] = __builtin_amdgcn_mfma_f32_16x16x32_bf16(a, bt1, acc2[to][1], 0, 0, 0);
    }
  }

  // ---- epilogue: out = x + ffn + b2 ----
#pragma unroll
  for (int to = 0; to < 8; ++to) {
    const int ob = to * 16 + fh * 4;
    const float4 bb = *(const float4*)(b2 + ob);
#pragma unroll
    for (int tp = 0; tp < 2; ++tp) {
#pragma unroll
      for (int r = 0; r < 4; ++r) {
        const size_t idx = (((size_t)(b * CCH + ob + r)) << 16) + p0 + tp * 16 + fl;
        out[idx] = x[idx] + acc2[to][tp][r] + bb[r];
      }
    }
  }
}

extern "C" void kernel_launch(void* const* d_in, const int* in_sizes, int n_in,
                              void* d_out, int out_size, void* d_ws, size_t ws_size,
                              hipStream_t stream) {
  const float* x    = (const float*)d_in[0];
  const float* gn_w = (const float*)d_in[1];
  const float* gn_b = (const float*)d_in[2];
  const float* w1   = (const float*)d_in[3];
  const float* b1   = (const float*)d_in[4];
  const float* w2   = (const float*)d_in[5];
  const float* b2   = (const float*)d_in[6];
  float* out = (float*)d_out;

  char* ws = (char*)d_ws;
  float* partials = (float*)ws;                 // 8 KiB
  float* scale    = (float*)(ws + 8192);        // 4 KiB
  float* shift    = (float*)(ws + 12288);       // 4 KiB
  ushort* w2b     = (ushort*)(ws + 16384);      // 32 KiB
  ushort* W1b     = (ushort*)(ws + 49152);      // 256 KiB (8 batches)
  float* c1       = (float*)(ws + 311296);      // 4 KiB

  hipLaunchKernelGGL(prep_w2, dim3(16), dim3(256), 0, stream, w2, w2b);
  hipLaunchKernelGGL(stats_partial, dim3(1024), dim3(256), 0, stream, x, partials);
  hipLaunchKernelGGL(stats_finalize, dim3(1), dim3(64), 0, stream, partials, gn_w, gn_b, scale, shift);
  hipLaunchKernelGGL(fold_w1, dim3(1024), dim3(128), 0, stream, w1, b1, scale, shift, W1b, c1);
  hipLaunchKernelGGL(wave_fused, dim3(16384), dim3(64), 0, stream, x, W1b, w2b, c1, b2, out);
}